// Round 8
// baseline (128.227 us; speedup 1.0000x reference)
//
#include <hip/hip_runtime.h>

#define HD 10
#define C2 20
#define PIX (192*192)
#define NB 8
#define NPIX (NB*PIX)
#define CHW (NB*HD*PIX)
#define EPSB 1e-5f
#define PXB 512              // pixels per block (256 threads x 2)
#define BPB (PIX/PXB)        // blocks per (batch,half) image = 72

__device__ __forceinline__ float rsq_fast(float x) {
    return __builtin_amdgcn_rsqf(x);
}
__device__ __forceinline__ float sigm(float x) {
    return __builtin_amdgcn_rcpf(1.0f + __expf(-x));
}
__device__ __forceinline__ float tanh_fast(float x) {
    return 1.0f - 2.0f * __builtin_amdgcn_rcpf(1.0f + __expf(2.0f * x));
}
// move a wave-uniform float into an SGPR (frees a VGPR; legal as 1-SGPR FMA operand)
__device__ __forceinline__ float uni(float x) {
    return __int_as_float(__builtin_amdgcn_readfirstlane(__float_as_int(x)));
}

// 2 pixels/thread (float2 loads), halves interleaved on grid.x.
// Weights via wave-uniform scalar loads; each s_load chunk feeds TWO independent
// FMA chains (ILP x2 per stall window) - attacks the r7-diagnosed lgkmcnt stall.
// launch_bounds(256,2): VGPR cap 256 so nothing spills (r4 failed at cap 170).
__global__ __launch_bounds__(256, 2) void half_kernel(
    const float* __restrict__ xf, const float* __restrict__ xh, const float* __restrict__ xp,
    const float* __restrict__ h_att, const float* __restrict__ p_att,
    const float* __restrict__ dW1, const float* __restrict__ dbn1,
    const float* __restrict__ dW2, const float* __restrict__ dbn2,
    const float* __restrict__ uW1, const float* __restrict__ ubn1,
    const float* __restrict__ uW2, const float* __restrict__ ubn2,
    const float* __restrict__ lW1, const float* __restrict__ lbn1,
    const float* __restrict__ lW2, const float* __restrict__ lbn2,
    const float* __restrict__ guWg, const float* __restrict__ gubg,
    const float* __restrict__ guWc, const float* __restrict__ gubc,
    const float* __restrict__ glWg, const float* __restrict__ glbg,
    const float* __restrict__ glWc, const float* __restrict__ glbc,
    float* __restrict__ out)
{
    const int bid  = blockIdx.x;
    const int half = bid & 1;                    // interleaved for load balance
    const int bx   = bid >> 1;
    const int b    = bx / BPB;                   // uniform per block
    const int s    = (bx - b * BPB) * PXB + threadIdx.x * 2;
    const int base  = b * (HD*PIX) + s;          // [B,HD,P] tensors: + c*PIX
    const int abase = b * PIX + s;               // [*,B,1,P] attention maps

    const float* Wc1  = half ? lW1  : uW1;
    const float* cbn1 = half ? lbn1 : ubn1;
    const float* Wc2  = half ? lW2  : uW2;
    const float* cbn2 = half ? lbn2 : ubn2;
    const float* Wg = half ? glWg : guWg;
    const float* bg = half ? glbg : gubg;
    const float* Wc = half ? glWc : guWc;
    const float* bc = half ? glbc : gubc;

    const float* xhh = xh + half * CHW;
    float* outh = out + half * CHW;

#define LD2(p, off) (*reinterpret_cast<const float2*>((p) + (off)))

    float vxhx[HD], vxhy[HD];
    #pragma unroll
    for (int c = 0; c < HD; ++c) {
        float2 v = LD2(xhh, base + c*PIX);
        vxhx[c] = v.x; vxhy[c] = v.y;
    }

    const float2 hav = LD2(h_att, (1 + half) * NPIX + abase);
    float cax = 0.f, cay = 0.f;
    {
        const int mstart = half ? 5 : 1;
        const int natt   = half ? 2 : 4;
        #pragma unroll
        for (int j = 0; j < 4; ++j)
            if (j < natt) {
                float2 v = LD2(p_att, (mstart + j) * NPIX + abase);
                cax += v.x; cay += v.y;
            }
    }

    // ---- decomposition block -> message accumulators ----
    float mx[HD], my[HD];
    {
        float fx[HD], fy[HD];
        #pragma unroll
        for (int c = 0; c < HD; ++c) {
            float2 v = LD2(xf, base + c*PIX);
            fx[c] = v.x * hav.x; fy[c] = v.y * hav.y;
        }
        float hx[C2], hy[C2];
        #pragma unroll
        for (int o = 0; o < C2; ++o) {
            float ax = 0.f, ay = 0.f;
            #pragma unroll
            for (int k = 0; k < HD; ++k) {
                float w = dW1[o*C2 + k];
                ax = fmaf(w, fx[k], ax); ay = fmaf(w, fy[k], ay);
            }
            #pragma unroll
            for (int k = 0; k < HD; ++k) {
                float w = dW1[o*C2 + HD + k];
                ax = fmaf(w, vxhx[k], ax); ay = fmaf(w, vxhy[k], ay);
            }
            float sc = dbn1[o] * rsq_fast(dbn1[3*C2 + o] + EPSB);
            float tr = dbn1[C2 + o] - sc * dbn1[2*C2 + o];
            hx[o] = fmaxf(fmaf(ax, sc, tr), 0.f);
            hy[o] = fmaxf(fmaf(ay, sc, tr), 0.f);
        }
        #pragma unroll
        for (int o = 0; o < HD; ++o) {
            float ax = 0.f, ay = 0.f;
            #pragma unroll
            for (int k = 0; k < C2; ++k) {
                float w = dW2[o*C2 + k];
                ax = fmaf(w, hx[k], ax); ay = fmaf(w, hy[k], ay);
            }
            float sc = dbn2[o] * rsq_fast(dbn2[3*HD + o] + EPSB);
            float tr = dbn2[HD + o] - sc * dbn2[2*HD + o];
            mx[o] = fmaxf(fmaf(ax, sc, tr), 0.f);
            my[o] = fmaxf(fmaf(ay, sc, tr), 0.f);
        }
    }

    // ---- composition blocks ----
    {
        float s1[C2], s2[HD], t2[HD];
        #pragma unroll
        for (int o = 0; o < C2; ++o)
            s1[o] = uni(cbn1[o] * rsq_fast(cbn1[3*C2 + o] + EPSB));   // SGPR
        #pragma unroll
        for (int o = 0; o < HD; ++o) {
            s2[o] = uni(cbn2[o] * rsq_fast(cbn2[3*HD + o] + EPSB));   // SGPR
            t2[o] = cbn2[HD + o] - s2[o] * cbn2[2*HD + o];            // VGPR
        }
        float prex[C2], prey[C2];
        #pragma unroll
        for (int o = 0; o < C2; ++o) {
            float ax = 0.f, ay = 0.f;
            #pragma unroll
            for (int k = 0; k < HD; ++k) {
                float w = Wc1[o*C2 + k];
                ax = fmaf(w, vxhx[k], ax); ay = fmaf(w, vxhy[k], ay);
            }
            float t1 = cbn1[C2 + o] - s1[o] * cbn1[2*C2 + o];
            prex[o] = fmaf(ax, s1[o], t1);
            prey[o] = fmaf(ay, s1[o], t1);
        }
        const int pstart = half ? 4 : 0;
        const int nparts = half ? 2 : 4;
        #pragma unroll
        for (int i = 0; i < 4; ++i) {
            if (i < nparts) {                    // wave-uniform guard
                float px[HD], py[HD];
                #pragma unroll
                for (int c = 0; c < HD; ++c) {
                    float2 v = LD2(xp, (pstart + i) * CHW + base + c*PIX);
                    px[c] = v.x * cax; py[c] = v.y * cay;
                }
                float hx[C2], hy[C2];
                #pragma unroll
                for (int o = 0; o < C2; ++o) {
                    float ax = 0.f, ay = 0.f;
                    #pragma unroll
                    for (int k = 0; k < HD; ++k) {
                        float w = Wc1[o*C2 + HD + k];
                        ax = fmaf(w, px[k], ax); ay = fmaf(w, py[k], ay);
                    }
                    hx[o] = fmaxf(fmaf(ax, s1[o], prex[o]), 0.f);
                    hy[o] = fmaxf(fmaf(ay, s1[o], prey[o]), 0.f);
                }
                #pragma unroll
                for (int o = 0; o < HD; ++o) {
                    float ax = 0.f, ay = 0.f;
                    #pragma unroll
                    for (int k = 0; k < C2; ++k) {
                        float w = Wc2[o*C2 + k];
                        ax = fmaf(w, hx[k], ax); ay = fmaf(w, hy[k], ay);
                    }
                    mx[o] += fmaxf(fmaf(ax, s2[o], t2[o]), 0.f);
                    my[o] += fmaxf(fmaf(ay, s2[o], t2[o]), 0.f);
                }
            }
        }
    }

    // ---- GRU ----
    float gx[C2], gy[C2];
    #pragma unroll
    for (int o = 0; o < C2; ++o) {
        float ax = bg[o], ay = ax;
        #pragma unroll
        for (int k = 0; k < HD; ++k) {
            float w = Wg[o*C2 + k];
            ax = fmaf(w, mx[k], ax); ay = fmaf(w, my[k], ay);
        }
        #pragma unroll
        for (int k = 0; k < HD; ++k) {
            float w = Wg[o*C2 + HD + k];
            ax = fmaf(w, vxhx[k], ax); ay = fmaf(w, vxhy[k], ay);
        }
        gx[o] = sigm(ax); gy[o] = sigm(ay);
    }
    float rhx[HD], rhy[HD];
    #pragma unroll
    for (int k = 0; k < HD; ++k) {
        rhx[k] = gx[k] * vxhx[k];
        rhy[k] = gy[k] * vxhy[k];
    }
    #pragma unroll
    for (int o = 0; o < HD; ++o) {
        float ax = bc[o], ay = ax;
        #pragma unroll
        for (int k = 0; k < HD; ++k) {
            float w = Wc[o*C2 + k];
            ax = fmaf(w, mx[k], ax); ay = fmaf(w, my[k], ay);
        }
        #pragma unroll
        for (int k = 0; k < HD; ++k) {
            float w = Wc[o*C2 + HD + k];
            ax = fmaf(w, rhx[k], ax); ay = fmaf(w, rhy[k], ay);
        }
        float2 o2;
        o2.x = fmaf(gx[HD + o], tanh_fast(ax) - vxhx[o], vxhx[o]);
        o2.y = fmaf(gy[HD + o], tanh_fast(ay) - vxhy[o], vxhy[o]);
        *reinterpret_cast<float2*>(outh + base + o*PIX) = o2;
    }
#undef LD2
}

extern "C" void kernel_launch(void* const* d_in, const int* in_sizes, int n_in,
                              void* d_out, int out_size, void* d_ws, size_t ws_size,
                              hipStream_t stream) {
    const float* xf    = (const float*)d_in[0];
    const float* xh    = (const float*)d_in[1];
    const float* xp    = (const float*)d_in[2];
    const float* h_att = (const float*)d_in[3];
    const float* p_att = (const float*)d_in[4];
    const float* dW1   = (const float*)d_in[5];
    const float* dbn1  = (const float*)d_in[6];
    const float* dW2   = (const float*)d_in[7];
    const float* dbn2  = (const float*)d_in[8];
    const float* uW1   = (const float*)d_in[9];
    const float* ubn1  = (const float*)d_in[10];
    const float* uW2   = (const float*)d_in[11];
    const float* ubn2  = (const float*)d_in[12];
    const float* lW1   = (const float*)d_in[13];
    const float* lbn1  = (const float*)d_in[14];
    const float* lW2   = (const float*)d_in[15];
    const float* lbn2  = (const float*)d_in[16];
    const float* guWg  = (const float*)d_in[17];
    const float* gubg  = (const float*)d_in[18];
    const float* guWc  = (const float*)d_in[19];
    const float* gubc  = (const float*)d_in[20];
    const float* glWg  = (const float*)d_in[21];
    const float* glbg  = (const float*)d_in[22];
    const float* glWc  = (const float*)d_in[23];
    const float* glbc  = (const float*)d_in[24];

    dim3 grid((NPIX / PXB) * 2), block(256);
    half_kernel<<<grid, block, 0, stream>>>(
        xf, xh, xp, h_att, p_att,
        dW1, dbn1, dW2, dbn2,
        uW1, ubn1, uW2, ubn2,
        lW1, lbn1, lW2, lbn2,
        guWg, gubg, guWc, gubc,
        glWg, glbg, glWc, glbc,
        (float*)d_out);
}